// Round 12
// baseline (56.510 us; speedup 1.0000x reference)
//
#include <hip/hip_runtime.h>

typedef _Float16 f16;
typedef __attribute__((ext_vector_type(8))) _Float16 f16x8;
typedef __attribute__((ext_vector_type(4))) _Float16 f16x4;
typedef __attribute__((ext_vector_type(4))) float f32x4;
typedef __attribute__((ext_vector_type(16))) float f32x16;

__device__ inline float lrelu(float v){ return v > 0.f ? v : 0.01f*v; }
__device__ inline f16x8 lrelu8(f16x8 v){
    f16x8 z = {};
    f16x8 mx = __builtin_elementwise_max(v, z);
    f16x8 mn = __builtin_elementwise_min(v, z);
    return mx + mn * (f16)0.01f;
}

__device__ __forceinline__ void gload16(const void* gp, void* lp) {
    __builtin_amdgcn_global_load_lds(
        (const __attribute__((address_space(1))) unsigned int*)gp,
        (__attribute__((address_space(3))) unsigned int*)lp,
        16, 0, 0);
}

#define M_ROWS 2048

// ======================= launch 1: all pure-weight prep =======================
//   [0,256)     Wct (FIRST: 31.5MB HBM stream starts at t=0)
//   [256,521)   prep_T ; [521,649) hW2t ; [649,777) bW2t ;
//   [777,1033)  oW2t   ; [1033,1097) oW3t ; [1097,1101) cards
#define P1_WCT  0
#define P1_T    256
#define P1_HW2  521
#define P1_BW2  649
#define P1_OW2  777
#define P1_OW3  1033
#define P1_CARD 1097
#define P1_END  1101

__device__ void d_transpose512(const float* __restrict__ in, f16* __restrict__ out,
                               int K, int Nin, int Nout, int b, int tid) {
    int idx = b * 512 + tid;
    if (idx >= Nout * K) return;
    int n = idx / K, k = idx - n * K;
    float v = (n < Nin) ? in[(size_t)k * Nin + n] : 0.f;
    out[idx] = (f16)v;
}

__global__ __launch_bounds__(512) void prep1(const int* __restrict__ x,
                                             const float* __restrict__ emb,
                                             const float* __restrict__ hW1,
                                             const float* __restrict__ hb1,
                                             const float* __restrict__ hW2,
                                             const float* __restrict__ bW1,
                                             const float* __restrict__ bb1,
                                             const float* __restrict__ bW2,
                                             const float* __restrict__ oW1,
                                             const float* __restrict__ oW2,
                                             const float* __restrict__ oW3,
                                             f16* __restrict__ T,
                                             f16* __restrict__ hW2t,
                                             f16* __restrict__ bW2t,
                                             f16* __restrict__ oW2t,
                                             f16* __restrict__ oW3t,
                                             f16* __restrict__ Wct,
                                             int* __restrict__ cid) {
    __shared__ float tile[64][65];
    const int bid = blockIdx.x, tid = threadIdx.x;
    if (bid < P1_T) {
        // ---------------- prep_Wct ----------------
        int kb = bid & 31, nb = bid >> 5;
        int nl = tid & 63;
        for (int kl = tid >> 6; kl < 64; kl += 8) {
            int col = kb * 64 + kl;
            int p = col >> 7, r = col & 127;
            int n = nb * 64 + nl;
            float s = 0.f;
            if (p < 6) {
                #pragma unroll
                for (int j = 0; j < 10; ++j) s += oW1[(size_t)((p * 10 + j) * 256 + r) * 512 + n];
            } else {
                int t = p - 6;
                #pragma unroll
                for (int i = 0; i < 6; ++i) s += oW1[(size_t)((i * 10 + t) * 256 + 128 + r) * 512 + n];
            }
            tile[kl][nl] = s;
        }
        __syncthreads();
        for (int nl2 = tid >> 6; nl2 < 64; nl2 += 8) {
            int kl2 = tid & 63;
            Wct[(size_t)(nb * 64 + nl2) * 2048 + kb * 64 + kl2] = (f16)tile[kl2][nl2];
        }
    } else if (bid < P1_HW2) {
        int b = bid - P1_T;          // slot*53 + card
        int slot = b / 53, card = b - slot * 53;
        const float* W = (slot < 2) ? (hW1 + slot * 64 * 512) : (bW1 + (slot - 2) * 64 * 512);
        const float* e = emb + card * 64;
        float acc = (slot == 1) ? hb1[tid] : ((slot == 4) ? bb1[tid] : 0.f);
        #pragma unroll 8
        for (int k = 0; k < 64; ++k) acc += e[k] * W[k * 512 + tid];
        T[(size_t)b * 512 + tid] = (f16)acc;
    } else if (bid < P1_BW2) {
        d_transpose512(hW2, hW2t, 512, 128, 128, bid - P1_HW2, tid);
    } else if (bid < P1_OW2) {
        d_transpose512(bW2, bW2t, 512, 128, 128, bid - P1_BW2, tid);
    } else if (bid < P1_OW3) {
        d_transpose512(oW2, oW2t, 512, 256, 256, bid - P1_OW2, tid);
    } else if (bid < P1_CARD) {
        d_transpose512(oW3, oW3t, 256, 127, 128, bid - P1_OW3, tid);
    } else {
        int m = (bid - P1_CARD) * 512 + tid;
        if (m >= M_ROWS) return;
        int kh[4], kb[5];
        #pragma unroll
        for (int i = 0; i < 4; ++i) { int r = x[m*18 + 2*i], s = x[m*18 + 2*i + 1]; kh[i] = r*8 + s; }
        #pragma unroll
        for (int i = 0; i < 5; ++i) { int r = x[m*18 + 8 + 2*i], s = x[m*18 + 9 + 2*i]; kb[i] = r*8 + s; }
        #pragma unroll
        for (int i = 1; i < 4; ++i) { int v = kh[i], j = i-1; while (j >= 0 && kh[j] > v) { kh[j+1]=kh[j]; --j; } kh[j+1]=v; }
        #pragma unroll
        for (int i = 1; i < 5; ++i) { int v = kb[i], j = i-1; while (j >= 0 && kb[j] > v) { kb[j+1]=kb[j]; --j; } kb[j+1]=v; }
        #pragma unroll
        for (int i = 0; i < 4; ++i) { int r = kh[i] >> 3, s = kh[i] & 7; cid[m*9 + i] = (r - 1) * s; }
        #pragma unroll
        for (int i = 0; i < 5; ++i) { int r = kb[i] >> 3, s = kb[i] & 7; cid[m*9 + 4 + i] = (r - 1) * s; }
    }
}

// ===== launch 2 (mega): pure l2_fused, 512 blocks, 32x32x16 MFMA =====
__global__ __launch_bounds__(512, 4) void mega(const int* __restrict__ cid,
                                               const f16* __restrict__ T,
                                               const f16* __restrict__ hW2t,
                                               const f16* __restrict__ bW2t,
                                               const float* __restrict__ hb2,
                                               const float* __restrict__ bb2,
                                               f16* __restrict__ X) {
    __shared__ __align__(16) char smem[51200];
    const int bid = blockIdx.x, tid = threadIdx.x;

    // ------- l2_fused: tile 64 rows x 128 cols, K=512, 8 waves of 32r x 32c -------
    f16 (*As)[64*64]  = (f16(*)[64*64])smem;               // 2 x 8KB  (swizzled)
    f16 (*Bs)[128*64] = (f16(*)[128*64])(smem + 16384);    // 2 x 16KB (swizzled)
    const bool hero = bid < 192;
    const int row0 = hero ? bid * 64 : (bid - 192) * 64;
    const f16* Bt = hero ? hW2t : bW2t;
    const float* bias = hero ? hb2 : bb2;
    const int lane = tid & 63, wave = tid >> 6;
    const int rw = wave & 1, cw = wave >> 1;   // 2 rowg x 4 colg
    const int l31 = lane & 31, lh = lane >> 5;

    const int br = tid >> 3, bchunk = tid & 7;   // A-build: row br, chunk bchunk
    const int grow = row0 + br;
    const f16 *t0, *t1, *t2;
    if (hero) {
        const int HP0[6] = {0,0,0,1,1,2}, HP1[6] = {1,2,3,2,3,3};
        int m = grow / 6, p = grow - m * 6;
        t0 = T + (size_t)(0*53 + cid[m*9 + HP0[p]]) * 512;
        t1 = T + (size_t)(1*53 + cid[m*9 + HP1[p]]) * 512;
        t2 = T;   // slot0 card0 == all zeros
    } else {
        const int BT0[10] = {4,4,4,4,4,4,5,5,5,6};
        const int BT1[10] = {5,5,5,6,6,7,6,6,7,7};
        const int BT2[10] = {6,7,8,7,8,8,7,8,8,8};
        int m = grow / 10, t = grow - m * 10;
        t0 = T + (size_t)(2*53 + cid[m*9 + BT0[t]]) * 512;
        t1 = T + (size_t)(3*53 + cid[m*9 + BT1[t]]) * 512;
        t2 = T + (size_t)(4*53 + cid[m*9 + BT2[t]]) * 512;
    }

    auto stageB = [&](int buf, int k0) {
        #pragma unroll
        for (int i = 0; i < 2; ++i) {
            int c = tid + i * 512;                 // 1024 chunks: 128 rows x 8
            int r = c >> 3, cc = c & 7;
            gload16(Bt + (size_t)r * 512 + k0 + ((cc ^ (r & 7)) << 3), (void*)&Bs[buf][c * 8]);
        }
    };
    auto buildA = [&](int buf, int k0) {
        f16x8 a = *(const f16x8*)(t0 + k0 + bchunk * 8);
        f16x8 b = *(const f16x8*)(t1 + k0 + bchunk * 8);
        f16x8 c = *(const f16x8*)(t2 + k0 + bchunk * 8);
        *(f16x8*)&As[buf][br * 64 + ((bchunk ^ (br & 7)) << 3)] = lrelu8(a + b + c);
    };

    f32x16 acc = {};
    stageB(0, 0); buildA(0, 0);
    __syncthreads();
    for (int t = 0; t < 8; ++t) {
        int cur = t & 1;
        if (t < 7) { stageB(cur ^ 1, (t + 1) * 64); buildA(cur ^ 1, (t + 1) * 64); }
        #pragma unroll
        for (int ks4 = 0; ks4 < 4; ++ks4) {
            int chunk = ks4 * 2 + lh;
            int ar = rw * 32 + l31, bcol = cw * 32 + l31;
            f16x8 a = *(const f16x8*)&As[cur][ar * 64 + ((chunk ^ (ar & 7)) << 3)];
            f16x8 b = *(const f16x8*)&Bs[cur][bcol * 64 + ((chunk ^ (bcol & 7)) << 3)];
            acc = __builtin_amdgcn_mfma_f32_32x32x16_f16(a, b, acc, 0, 0, 0);
        }
        __syncthreads();
    }
    #pragma unroll
    for (int q = 0; q < 16; ++q) {
        int row = row0 + rw * 32 + (q & 3) + 8 * (q >> 2) + 4 * lh;
        int col = cw * 32 + l31;
        float v = lrelu(acc[q] + bias[col]);
        size_t off;
        if (hero) { int m = row / 6,  p = row - m*6;  off = (size_t)m*2048 + p*128 + col; }
        else      { int m = row / 10, p = row - m*10; off = (size_t)m*2048 + 768 + p*128 + col; }
        X[off] = (f16)v;
    }
}

// ===== launch 3: combine, split-K=4, BN=128, XCD-swizzled, 32x32x16 MFMA =====
__global__ __launch_bounds__(512, 4) void combine(const f16* __restrict__ X,
                                                  const f16* __restrict__ Wct,
                                                  float* __restrict__ R1p) {
    __shared__ __align__(16) f16 As[2][64 * 64];    // 16KB
    __shared__ __align__(16) f16 Bs[2][128 * 64];   // 32KB
    const int bid = blockIdx.x;                     // 0..511
    const int xcd = bid & 7, slot = bid >> 3;       // slot 0..63
    const int rp = xcd * 4 + (slot & 3);            // row panel 0..31 (same rp -> same XCD)
    const int rest = slot >> 2;                     // 0..15
    const int cp = rest & 3, ks = rest >> 2;        // col panel 0..3, k-split 0..3
    const int row0 = rp * 64, col0 = cp * 128, k0b = ks * 512;
    const int tid = threadIdx.x, lane = tid & 63, wave = tid >> 6;
    const int rw = wave & 1, cw = wave >> 1;        // 2 rowg x 4 colg of 32
    const int l31 = lane & 31, lh = lane >> 5;

    auto stage = [&](int buf, int k0) {
        { int r = tid >> 3, cc = tid & 7;
          gload16(X + (size_t)(row0 + r) * 2048 + k0 + ((cc ^ (r & 7)) << 3), (void*)&As[buf][tid * 8]); }
        #pragma unroll
        for (int i = 0; i < 2; ++i) {
            int c = tid + i * 512;
            int r = c >> 3, cc = c & 7;
            gload16(Wct + (size_t)(col0 + r) * 2048 + k0 + ((cc ^ (r & 7)) << 3), (void*)&Bs[buf][c * 8]);
        }
    };

    f32x16 acc = {};
    stage(0, k0b);
    __syncthreads();
    for (int t = 0; t < 8; ++t) {
        int cur = t & 1;
        if (t < 7) stage(cur ^ 1, k0b + (t + 1) * 64);
        #pragma unroll
        for (int ks4 = 0; ks4 < 4; ++ks4) {
            int chunk = ks4 * 2 + lh;
            int ar = rw * 32 + l31, bcol = cw * 32 + l31;
            f16x8 a = *(const f16x8*)&As[cur][ar * 64 + ((chunk ^ (ar & 7)) << 3)];
            f16x8 b = *(const f16x8*)&Bs[cur][bcol * 64 + ((chunk ^ (bcol & 7)) << 3)];
            acc = __builtin_amdgcn_mfma_f32_32x32x16_f16(a, b, acc, 0, 0, 0);
        }
        __syncthreads();
    }
    float* dst = R1p + (size_t)ks * 2048 * 512;
    #pragma unroll
    for (int q = 0; q < 16; ++q) {
        int row = row0 + rw * 32 + (q & 3) + 8 * (q >> 2) + 4 * lh;
        int col = col0 + cw * 32 + l31;
        dst[(size_t)row * 512 + col] = acc[q];
    }
}

// ===== launch 4: tail2, 256 blocks x 8 rows. B read direct from L2 (no LDS, no
// staging barriers — oW2t 256KB / oW3t 64KB are L2-resident, reused by all blocks).
__global__ __launch_bounds__(512, 4) void tail2(const float* __restrict__ R1p,
                                                const float* __restrict__ ob1,
                                                const f16* __restrict__ oW2t,
                                                const float* __restrict__ ob2,
                                                const f16* __restrict__ oW3t,
                                                const float* __restrict__ ob3,
                                                const float* __restrict__ sW,
                                                const float* __restrict__ sb,
                                                float* __restrict__ out) {
    __shared__ __align__(16) f16 A1s[16 * 512];     // 16KB (rows 8-15 zeroed)
    __shared__ __align__(16) f16 R2s[16 * 256];     // 8KB (swizzled)
    __shared__ float R3s[16][132];                  // 8.4KB
    __shared__ float sWs[127 * 9];
    __shared__ float sbs[9];
    const int row0 = blockIdx.x * 8;
    const int tid = threadIdx.x, lane = tid & 63, wave = tid >> 6;
    const int lr = lane & 15, lq = lane >> 4;

    // --- phase A: A1[0:8] = lrelu(sum 4 R1p slices + ob1) -> swizzled f16; A1[8:16]=0 ---
    #pragma unroll
    for (int i = 0; i < 2; ++i) {
        int g = tid + i * 512;                      // 1024 f32x4 groups (8 rows x 128)
        int row = g >> 7, c4 = (g & 127) << 2;
        f32x4 v = *(const f32x4*)(ob1 + c4);
        #pragma unroll
        for (int s = 0; s < 4; ++s)
            v += *(const f32x4*)(R1p + (size_t)s * 2048 * 512 + (size_t)(row0 + row) * 512 + c4);
        f16x4 p;
        #pragma unroll
        for (int q = 0; q < 4; ++q) p[q] = (f16)lrelu(v[q]);
        int chunk = c4 >> 3, half = (c4 >> 2) & 1;
        *(f16x4*)&A1s[row * 512 + ((chunk ^ (row & 7)) << 3) + half * 4] = p;
    }
    {   // zero rows 8..15 (512 f16x8 chunks)
        f16x8 z = {};
        int row = 8 + (tid >> 6), chunk = tid & 63;
        *(f16x8*)&A1s[row * 512 + chunk * 8] = z;
    }
    for (int i = tid; i < 127 * 9; i += 512) sWs[i] = sW[i];
    if (tid < 9) sbs[tid] = sb[tid];
    __syncthreads();

    // --- phase B: R2 = lrelu(A1 @ oW2t^T + ob2), 16(8 valid)x256, K=512 ---
    // B frags straight from global (L2); K-parity split accumulators; no barriers.
    const f16* pB0 = oW2t + (size_t)(wave * 32 + lr) * 512      + lq * 8;
    const f16* pB1 = oW2t + (size_t)(wave * 32 + 16 + lr) * 512 + lq * 8;
    f32x4 acc2[2][2] = {};
    #pragma unroll
    for (int t = 0; t < 8; ++t) {
        int par = t & 1;
        #pragma unroll
        for (int kk2 = 0; kk2 < 2; ++kk2) {
            int g  = kk2 * 4 + lq;
            int gg = t * 8 + g;
            f16x8 a  = *(const f16x8*)&A1s[lr * 512 + ((gg ^ (lr & 7)) << 3)];
            f16x8 b0 = *(const f16x8*)(pB0 + t * 64 + kk2 * 32);
            f16x8 b1 = *(const f16x8*)(pB1 + t * 64 + kk2 * 32);
            acc2[0][par] = __builtin_amdgcn_mfma_f32_16x16x32_f16(a, b0, acc2[0][par], 0, 0, 0);
            acc2[1][par] = __builtin_amdgcn_mfma_f32_16x16x32_f16(a, b1, acc2[1][par], 0, 0, 0);
        }
    }
    #pragma unroll
    for (int j = 0; j < 2; ++j)
    #pragma unroll
    for (int q = 0; q < 4; ++q) {
        int row = lq * 4 + q;                       // rows 8-15 finite, unused
        int col = wave * 32 + j * 16 + lr;
        f16 v = (f16)lrelu(acc2[j][0][q] + acc2[j][1][q] + ob2[col]);
        int chunk = col >> 3, w = col & 7;
        R2s[row * 256 + ((chunk ^ (row & 7)) << 3) + w] = v;
    }
    __syncthreads();

    // --- phase C: R3 = lrelu(R2 @ oW3t^T + ob3), 16(8 valid)x128, K=256 ---
    const f16* pC = oW3t + (size_t)(wave * 16 + lr) * 256 + lq * 8;
    f32x4 acc3[2] = {};
    #pragma unroll
    for (int t = 0; t < 4; ++t) {
        int par = t & 1;
        #pragma unroll
        for (int kk2 = 0; kk2 < 2; ++kk2) {
            int g  = kk2 * 4 + lq;
            int gg = t * 8 + g;
            f16x8 a = *(const f16x8*)&R2s[lr * 256 + ((gg ^ (lr & 7)) << 3)];
            f16x8 b = *(const f16x8*)(pC + t * 64 + kk2 * 32);
            acc3[par] = __builtin_amdgcn_mfma_f32_16x16x32_f16(a, b, acc3[par], 0, 0, 0);
        }
    }
    #pragma unroll
    for (int q = 0; q < 4; ++q) {
        int row = lq * 4 + q;
        int col = wave * 16 + lr;
        R3s[row][col] = lrelu(acc3[0][q] + acc3[1][q] + ((col < 127) ? ob3[col] : 0.f));
    }
    __syncthreads();

    // --- phase D: out = R3 @ sW + sb (rows 0..7 only) ---
    if (tid < 8 * 9) {
        int row = tid / 9, a = tid - row * 9;
        float s = sbs[a];
        #pragma unroll 4
        for (int n = 0; n < 127; ++n) s += R3s[row][n] * sWs[n * 9 + a];
        out[(size_t)(row0 + row) * 9 + a] = s;
    }
}

extern "C" void kernel_launch(void* const* d_in, const int* in_sizes, int n_in,
                              void* d_out, int out_size, void* d_ws, size_t ws_size,
                              hipStream_t stream) {
    const int*   x    = (const int*)  d_in[0];
    const float* emb  = (const float*)d_in[1];
    const float* hW1  = (const float*)d_in[2];
    const float* hb1  = (const float*)d_in[3];
    const float* hW2  = (const float*)d_in[4];
    const float* hb2  = (const float*)d_in[5];
    const float* bW1  = (const float*)d_in[6];
    const float* bb1  = (const float*)d_in[7];
    const float* bW2  = (const float*)d_in[8];
    const float* bb2  = (const float*)d_in[9];
    const float* oW1  = (const float*)d_in[10];
    const float* ob1  = (const float*)d_in[11];
    const float* oW2  = (const float*)d_in[12];
    const float* ob2  = (const float*)d_in[13];
    const float* oW3  = (const float*)d_in[14];
    const float* ob3  = (const float*)d_in[15];
    const float* sW   = (const float*)d_in[16];
    const float* sb   = (const float*)d_in[17];

    char* ws = (char*)d_ws;
    constexpr size_t OFF_T    = 0;                     // 5*53*512 f16   =   271,360
    constexpr size_t OFF_HW2T = 271360;                // 128x512 f16    =   131,072
    constexpr size_t OFF_BW2T = 402432;                // 128x512 f16    =   131,072
    constexpr size_t OFF_OW2T = 533504;                // 256x512 f16    =   262,144
    constexpr size_t OFF_OW3T = 795648;                // 128x256 f16    =    65,536
    constexpr size_t OFF_WCT  = 861184;                // 512x2048 f16   = 2,097,152
    constexpr size_t OFF_CID  = 2958336;               // 2048x9 i32     =    73,728
    constexpr size_t OFF_X    = 3032064;               // 2048x2048 f16  = 8,388,608
    constexpr size_t OFF_R1P  = 11420672;              // 4x2048x512 f32 = 16,777,216

    f16*   T    = (f16*)(ws + OFF_T);
    f16*   hW2t = (f16*)(ws + OFF_HW2T);
    f16*   bW2t = (f16*)(ws + OFF_BW2T);
    f16*   oW2t = (f16*)(ws + OFF_OW2T);
    f16*   oW3t = (f16*)(ws + OFF_OW3T);
    f16*   Wct  = (f16*)(ws + OFF_WCT);
    int*   cid  = (int*)(ws + OFF_CID);
    f16*   X    = (f16*)(ws + OFF_X);
    float* R1p  = (float*)(ws + OFF_R1P);

    prep1<<<P1_END, 512, 0, stream>>>(x, emb, hW1, hb1, hW2, bW1, bb1, bW2,
                                      oW1, oW2, oW3,
                                      T, hW2t, bW2t, oW2t, oW3t, Wct, cid);
    mega<<<512, 512, 0, stream>>>(cid, T, hW2t, bW2t, hb2, bb2, X);
    combine<<<512, 512, 0, stream>>>(X, Wct, R1p);
    tail2<<<256, 512, 0, stream>>>(R1p, ob1, oW2t, ob2, oW3t, ob3, sW, sb, (float*)d_out);
}

// Round 13
// 55.177 us; speedup vs baseline: 1.0242x; 1.0242x over previous
//
#include <hip/hip_runtime.h>

typedef _Float16 f16;
typedef __attribute__((ext_vector_type(8))) _Float16 f16x8;
typedef __attribute__((ext_vector_type(4))) _Float16 f16x4;
typedef __attribute__((ext_vector_type(4))) float f32x4;
typedef __attribute__((ext_vector_type(16))) float f32x16;

__device__ inline float lrelu(float v){ return v > 0.f ? v : 0.01f*v; }
__device__ inline f16x8 lrelu8(f16x8 v){
    f16x8 z = {};
    f16x8 mx = __builtin_elementwise_max(v, z);
    f16x8 mn = __builtin_elementwise_min(v, z);
    return mx + mn * (f16)0.01f;
}

__device__ __forceinline__ void gload16(const void* gp, void* lp) {
    __builtin_amdgcn_global_load_lds(
        (const __attribute__((address_space(1))) unsigned int*)gp,
        (__attribute__((address_space(3))) unsigned int*)lp,
        16, 0, 0);
}

#define M_ROWS 2048

// ======================= launch 1: all pure-weight prep (no Wct) =======================
//   [0,265)    prep_T ; [265,393) hW2t ; [393,521) bW2t ;
//   [521,777)  oW2t   ; [777,841) oW3t ; [841,845) cards
#define P1_T    0
#define P1_HW2  265
#define P1_BW2  393
#define P1_OW2  521
#define P1_OW3  777
#define P1_CARD 841
#define P1_END  845

__device__ void d_transpose512(const float* __restrict__ in, f16* __restrict__ out,
                               int K, int Nin, int Nout, int b, int tid) {
    int idx = b * 512 + tid;
    if (idx >= Nout * K) return;
    int n = idx / K, k = idx - n * K;
    float v = (n < Nin) ? in[(size_t)k * Nin + n] : 0.f;
    out[idx] = (f16)v;
}

__global__ __launch_bounds__(512) void prep1(const int* __restrict__ x,
                                             const float* __restrict__ emb,
                                             const float* __restrict__ hW1,
                                             const float* __restrict__ hb1,
                                             const float* __restrict__ hW2,
                                             const float* __restrict__ bW1,
                                             const float* __restrict__ bb1,
                                             const float* __restrict__ bW2,
                                             const float* __restrict__ oW2,
                                             const float* __restrict__ oW3,
                                             f16* __restrict__ T,
                                             f16* __restrict__ hW2t,
                                             f16* __restrict__ bW2t,
                                             f16* __restrict__ oW2t,
                                             f16* __restrict__ oW3t,
                                             int* __restrict__ cid) {
    const int bid = blockIdx.x, tid = threadIdx.x;
    if (bid < P1_HW2) {
        int b = bid;                 // slot*53 + card
        int slot = b / 53, card = b - slot * 53;
        const float* W = (slot < 2) ? (hW1 + slot * 64 * 512) : (bW1 + (slot - 2) * 64 * 512);
        const float* e = emb + card * 64;
        float acc = (slot == 1) ? hb1[tid] : ((slot == 4) ? bb1[tid] : 0.f);
        #pragma unroll 8
        for (int k = 0; k < 64; ++k) acc += e[k] * W[k * 512 + tid];
        T[(size_t)b * 512 + tid] = (f16)acc;
    } else if (bid < P1_BW2) {
        d_transpose512(hW2, hW2t, 512, 128, 128, bid - P1_HW2, tid);
    } else if (bid < P1_OW2) {
        d_transpose512(bW2, bW2t, 512, 128, 128, bid - P1_BW2, tid);
    } else if (bid < P1_OW3) {
        d_transpose512(oW2, oW2t, 512, 256, 256, bid - P1_OW2, tid);
    } else if (bid < P1_CARD) {
        d_transpose512(oW3, oW3t, 256, 127, 128, bid - P1_OW3, tid);
    } else {
        int m = (bid - P1_CARD) * 512 + tid;
        if (m >= M_ROWS) return;
        int kh[4], kb[5];
        #pragma unroll
        for (int i = 0; i < 4; ++i) { int r = x[m*18 + 2*i], s = x[m*18 + 2*i + 1]; kh[i] = r*8 + s; }
        #pragma unroll
        for (int i = 0; i < 5; ++i) { int r = x[m*18 + 8 + 2*i], s = x[m*18 + 9 + 2*i]; kb[i] = r*8 + s; }
        #pragma unroll
        for (int i = 1; i < 4; ++i) { int v = kh[i], j = i-1; while (j >= 0 && kh[j] > v) { kh[j+1]=kh[j]; --j; } kh[j+1]=v; }
        #pragma unroll
        for (int i = 1; i < 5; ++i) { int v = kb[i], j = i-1; while (j >= 0 && kb[j] > v) { kb[j+1]=kb[j]; --j; } kb[j+1]=v; }
        #pragma unroll
        for (int i = 0; i < 4; ++i) { int r = kh[i] >> 3, s = kh[i] & 7; cid[m*9 + i] = (r - 1) * s; }
        #pragma unroll
        for (int i = 0; i < 5; ++i) { int r = kb[i] >> 3, s = kb[i] & 7; cid[m*9 + 4 + i] = (r - 1) * s; }
    }
}

// ===== launch 2 (mega): Wct (first: starts HBM stream, overlaps l2) + l2_fused =====
#define MG_L2   256
#define MG_END  768

__global__ __launch_bounds__(512, 4) void mega(const int* __restrict__ cid,
                                               const f16* __restrict__ T,
                                               const f16* __restrict__ hW2t,
                                               const f16* __restrict__ bW2t,
                                               const float* __restrict__ hb2,
                                               const float* __restrict__ bb2,
                                               const float* __restrict__ oW1,
                                               f16* __restrict__ X,
                                               f16* __restrict__ Wct) {
    __shared__ __align__(16) char smem[51200];
    const int bid = blockIdx.x, tid = threadIdx.x;

    if (bid < MG_L2) {
        // ---------------- prep_Wct ----------------
        float (*tile)[65] = (float(*)[65])smem;
        int kb = bid & 31, nb = bid >> 5;
        int nl = tid & 63;
        for (int kl = tid >> 6; kl < 64; kl += 8) {
            int col = kb * 64 + kl;
            int p = col >> 7, r = col & 127;
            int n = nb * 64 + nl;
            float s = 0.f;
            if (p < 6) {
                #pragma unroll
                for (int j = 0; j < 10; ++j) s += oW1[(size_t)((p * 10 + j) * 256 + r) * 512 + n];
            } else {
                int t = p - 6;
                #pragma unroll
                for (int i = 0; i < 6; ++i) s += oW1[(size_t)((i * 10 + t) * 256 + 128 + r) * 512 + n];
            }
            tile[kl][nl] = s;
        }
        __syncthreads();
        for (int nl2 = tid >> 6; nl2 < 64; nl2 += 8) {
            int kl2 = tid & 63;
            Wct[(size_t)(nb * 64 + nl2) * 2048 + kb * 64 + kl2] = (f16)tile[kl2][nl2];
        }
        return;
    }

    // ------- l2_fused: tile 64 rows x 128 cols, K=512, 8 waves of 32r x 32c -------
    f16 (*As)[64*64]  = (f16(*)[64*64])smem;               // 2 x 8KB  (swizzled)
    f16 (*Bs)[128*64] = (f16(*)[128*64])(smem + 16384);    // 2 x 16KB (swizzled)
    const int lbid = bid - MG_L2;
    const bool hero = lbid < 192;
    const int row0 = hero ? lbid * 64 : (lbid - 192) * 64;
    const f16* Bt = hero ? hW2t : bW2t;
    const float* bias = hero ? hb2 : bb2;
    const int lane = tid & 63, wave = tid >> 6;
    const int rw = wave & 1, cw = wave >> 1;   // 2 rowg x 4 colg
    const int l31 = lane & 31, lh = lane >> 5;

    const int br = tid >> 3, bchunk = tid & 7;   // A-build: row br, chunk bchunk
    const int grow = row0 + br;
    const f16 *t0, *t1, *t2;
    if (hero) {
        const int HP0[6] = {0,0,0,1,1,2}, HP1[6] = {1,2,3,2,3,3};
        int m = grow / 6, p = grow - m * 6;
        t0 = T + (size_t)(0*53 + cid[m*9 + HP0[p]]) * 512;
        t1 = T + (size_t)(1*53 + cid[m*9 + HP1[p]]) * 512;
        t2 = T;   // slot0 card0 == all zeros
    } else {
        const int BT0[10] = {4,4,4,4,4,4,5,5,5,6};
        const int BT1[10] = {5,5,5,6,6,7,6,6,7,7};
        const int BT2[10] = {6,7,8,7,8,8,7,8,8,8};
        int m = grow / 10, t = grow - m * 10;
        t0 = T + (size_t)(2*53 + cid[m*9 + BT0[t]]) * 512;
        t1 = T + (size_t)(3*53 + cid[m*9 + BT1[t]]) * 512;
        t2 = T + (size_t)(4*53 + cid[m*9 + BT2[t]]) * 512;
    }

    auto stageB = [&](int buf, int k0) {
        #pragma unroll
        for (int i = 0; i < 2; ++i) {
            int c = tid + i * 512;                 // 1024 chunks: 128 rows x 8
            int r = c >> 3, cc = c & 7;
            gload16(Bt + (size_t)r * 512 + k0 + ((cc ^ (r & 7)) << 3), (void*)&Bs[buf][c * 8]);
        }
    };
    auto buildA = [&](int buf, int k0) {
        f16x8 a = *(const f16x8*)(t0 + k0 + bchunk * 8);
        f16x8 b = *(const f16x8*)(t1 + k0 + bchunk * 8);
        f16x8 c = *(const f16x8*)(t2 + k0 + bchunk * 8);
        *(f16x8*)&As[buf][br * 64 + ((bchunk ^ (br & 7)) << 3)] = lrelu8(a + b + c);
    };

    f32x16 acc = {};
    stageB(0, 0); buildA(0, 0);
    __syncthreads();
    for (int t = 0; t < 8; ++t) {
        int cur = t & 1;
        if (t < 7) { stageB(cur ^ 1, (t + 1) * 64); buildA(cur ^ 1, (t + 1) * 64); }
        #pragma unroll
        for (int ks4 = 0; ks4 < 4; ++ks4) {
            int chunk = ks4 * 2 + lh;
            int ar = rw * 32 + l31, bcol = cw * 32 + l31;
            f16x8 a = *(const f16x8*)&As[cur][ar * 64 + ((chunk ^ (ar & 7)) << 3)];
            f16x8 b = *(const f16x8*)&Bs[cur][bcol * 64 + ((chunk ^ (bcol & 7)) << 3)];
            acc = __builtin_amdgcn_mfma_f32_32x32x16_f16(a, b, acc, 0, 0, 0);
        }
        __syncthreads();
    }
    #pragma unroll
    for (int q = 0; q < 16; ++q) {
        int row = row0 + rw * 32 + (q & 3) + 8 * (q >> 2) + 4 * lh;
        int col = cw * 32 + l31;
        float v = lrelu(acc[q] + bias[col]);
        size_t off;
        if (hero) { int m = row / 6,  p = row - m*6;  off = (size_t)m*2048 + p*128 + col; }
        else      { int m = row / 10, p = row - m*10; off = (size_t)m*2048 + 768 + p*128 + col; }
        X[off] = (f16)v;
    }
}

// ===== launch 3: combine, split-K=4, BN=128, XCD-swizzled, 32x32x16 MFMA =====
__global__ __launch_bounds__(512, 4) void combine(const f16* __restrict__ X,
                                                  const f16* __restrict__ Wct,
                                                  float* __restrict__ R1p) {
    __shared__ __align__(16) f16 As[2][64 * 64];    // 16KB
    __shared__ __align__(16) f16 Bs[2][128 * 64];   // 32KB
    const int bid = blockIdx.x;                     // 0..511
    const int xcd = bid & 7, slot = bid >> 3;       // slot 0..63
    const int rp = xcd * 4 + (slot & 3);            // row panel 0..31 (same rp -> same XCD)
    const int rest = slot >> 2;                     // 0..15
    const int cp = rest & 3, ks = rest >> 2;        // col panel 0..3, k-split 0..3
    const int row0 = rp * 64, col0 = cp * 128, k0b = ks * 512;
    const int tid = threadIdx.x, lane = tid & 63, wave = tid >> 6;
    const int rw = wave & 1, cw = wave >> 1;        // 2 rowg x 4 colg of 32
    const int l31 = lane & 31, lh = lane >> 5;

    auto stage = [&](int buf, int k0) {
        { int r = tid >> 3, cc = tid & 7;
          gload16(X + (size_t)(row0 + r) * 2048 + k0 + ((cc ^ (r & 7)) << 3), (void*)&As[buf][tid * 8]); }
        #pragma unroll
        for (int i = 0; i < 2; ++i) {
            int c = tid + i * 512;
            int r = c >> 3, cc = c & 7;
            gload16(Wct + (size_t)(col0 + r) * 2048 + k0 + ((cc ^ (r & 7)) << 3), (void*)&Bs[buf][c * 8]);
        }
    };

    f32x16 acc = {};
    stage(0, k0b);
    __syncthreads();
    for (int t = 0; t < 8; ++t) {
        int cur = t & 1;
        if (t < 7) stage(cur ^ 1, k0b + (t + 1) * 64);
        #pragma unroll
        for (int ks4 = 0; ks4 < 4; ++ks4) {
            int chunk = ks4 * 2 + lh;
            int ar = rw * 32 + l31, bcol = cw * 32 + l31;
            f16x8 a = *(const f16x8*)&As[cur][ar * 64 + ((chunk ^ (ar & 7)) << 3)];
            f16x8 b = *(const f16x8*)&Bs[cur][bcol * 64 + ((chunk ^ (bcol & 7)) << 3)];
            acc = __builtin_amdgcn_mfma_f32_32x32x16_f16(a, b, acc, 0, 0, 0);
        }
        __syncthreads();
    }
    float* dst = R1p + (size_t)ks * 2048 * 512;
    #pragma unroll
    for (int q = 0; q < 16; ++q) {
        int row = row0 + rw * 32 + (q & 3) + 8 * (q >> 2) + 4 * lh;
        int col = col0 + cw * 32 + l31;
        dst[(size_t)row * 512 + col] = acc[q];
    }
}

// ===== launch 4: tail2, 256 blocks x 8 rows. B read direct from L2 (no LDS staging).
__global__ __launch_bounds__(512, 4) void tail2(const float* __restrict__ R1p,
                                                const float* __restrict__ ob1,
                                                const f16* __restrict__ oW2t,
                                                const float* __restrict__ ob2,
                                                const f16* __restrict__ oW3t,
                                                const float* __restrict__ ob3,
                                                const float* __restrict__ sW,
                                                const float* __restrict__ sb,
                                                float* __restrict__ out) {
    __shared__ __align__(16) f16 A1s[16 * 512];     // 16KB (rows 8-15 zeroed)
    __shared__ __align__(16) f16 R2s[16 * 256];     // 8KB (swizzled)
    __shared__ float R3s[16][132];                  // 8.4KB
    __shared__ float sWs[127 * 9];
    __shared__ float sbs[9];
    const int row0 = blockIdx.x * 8;
    const int tid = threadIdx.x, lane = tid & 63, wave = tid >> 6;
    const int lr = lane & 15, lq = lane >> 4;

    // --- phase A: A1[0:8] = lrelu(sum 4 R1p slices + ob1) -> swizzled f16; A1[8:16]=0 ---
    #pragma unroll
    for (int i = 0; i < 2; ++i) {
        int g = tid + i * 512;                      // 1024 f32x4 groups (8 rows x 128)
        int row = g >> 7, c4 = (g & 127) << 2;
        f32x4 v = *(const f32x4*)(ob1 + c4);
        #pragma unroll
        for (int s = 0; s < 4; ++s)
            v += *(const f32x4*)(R1p + (size_t)s * 2048 * 512 + (size_t)(row0 + row) * 512 + c4);
        f16x4 p;
        #pragma unroll
        for (int q = 0; q < 4; ++q) p[q] = (f16)lrelu(v[q]);
        int chunk = c4 >> 3, half = (c4 >> 2) & 1;
        *(f16x4*)&A1s[row * 512 + ((chunk ^ (row & 7)) << 3) + half * 4] = p;
    }
    {   // zero rows 8..15 (512 f16x8 chunks)
        f16x8 z = {};
        int row = 8 + (tid >> 6), chunk = tid & 63;
        *(f16x8*)&A1s[row * 512 + chunk * 8] = z;
    }
    for (int i = tid; i < 127 * 9; i += 512) sWs[i] = sW[i];
    if (tid < 9) sbs[tid] = sb[tid];
    __syncthreads();

    // --- phase B: R2 = lrelu(A1 @ oW2t^T + ob2), 16(8 valid)x256, K=512 ---
    const f16* pB0 = oW2t + (size_t)(wave * 32 + lr) * 512      + lq * 8;
    const f16* pB1 = oW2t + (size_t)(wave * 32 + 16 + lr) * 512 + lq * 8;
    f32x4 acc2[2][2] = {};
    #pragma unroll
    for (int t = 0; t < 8; ++t) {
        int par = t & 1;
        #pragma unroll
        for (int kk2 = 0; kk2 < 2; ++kk2) {
            int g  = kk2 * 4 + lq;
            int gg = t * 8 + g;
            f16x8 a  = *(const f16x8*)&A1s[lr * 512 + ((gg ^ (lr & 7)) << 3)];
            f16x8 b0 = *(const f16x8*)(pB0 + t * 64 + kk2 * 32);
            f16x8 b1 = *(const f16x8*)(pB1 + t * 64 + kk2 * 32);
            acc2[0][par] = __builtin_amdgcn_mfma_f32_16x16x32_f16(a, b0, acc2[0][par], 0, 0, 0);
            acc2[1][par] = __builtin_amdgcn_mfma_f32_16x16x32_f16(a, b1, acc2[1][par], 0, 0, 0);
        }
    }
    #pragma unroll
    for (int j = 0; j < 2; ++j)
    #pragma unroll
    for (int q = 0; q < 4; ++q) {
        int row = lq * 4 + q;                       // rows 8-15 finite, unused
        int col = wave * 32 + j * 16 + lr;
        f16 v = (f16)lrelu(acc2[j][0][q] + acc2[j][1][q] + ob2[col]);
        int chunk = col >> 3, w = col & 7;
        R2s[row * 256 + ((chunk ^ (row & 7)) << 3) + w] = v;
    }
    __syncthreads();

    // --- phase C: R3 = lrelu(R2 @ oW3t^T + ob3), 16(8 valid)x128, K=256 ---
    const f16* pC = oW3t + (size_t)(wave * 16 + lr) * 256 + lq * 8;
    f32x4 acc3[2] = {};
    #pragma unroll
    for (int t = 0; t < 4; ++t) {
        int par = t & 1;
        #pragma unroll
        for (int kk2 = 0; kk2 < 2; ++kk2) {
            int g  = kk2 * 4 + lq;
            int gg = t * 8 + g;
            f16x8 a = *(const f16x8*)&R2s[lr * 256 + ((gg ^ (lr & 7)) << 3)];
            f16x8 b = *(const f16x8*)(pC + t * 64 + kk2 * 32);
            acc3[par] = __builtin_amdgcn_mfma_f32_16x16x32_f16(a, b, acc3[par], 0, 0, 0);
        }
    }
    #pragma unroll
    for (int q = 0; q < 4; ++q) {
        int row = lq * 4 + q;
        int col = wave * 16 + lr;
        R3s[row][col] = lrelu(acc3[0][q] + acc3[1][q] + ((col < 127) ? ob3[col] : 0.f));
    }
    __syncthreads();

    // --- phase D: out = R3 @ sW + sb (rows 0..7 only) ---
    if (tid < 8 * 9) {
        int row = tid / 9, a = tid - row * 9;
        float s = sbs[a];
        #pragma unroll 4
        for (int n = 0; n < 127; ++n) s += R3s[row][n] * sWs[n * 9 + a];
        out[(size_t)(row0 + row) * 9 + a] = s;
    }
}

extern "C" void kernel_launch(void* const* d_in, const int* in_sizes, int n_in,
                              void* d_out, int out_size, void* d_ws, size_t ws_size,
                              hipStream_t stream) {
    const int*   x    = (const int*)  d_in[0];
    const float* emb  = (const float*)d_in[1];
    const float* hW1  = (const float*)d_in[2];
    const float* hb1  = (const float*)d_in[3];
    const float* hW2  = (const float*)d_in[4];
    const float* hb2  = (const float*)d_in[5];
    const float* bW1  = (const float*)d_in[6];
    const float* bb1  = (const float*)d_in[7];
    const float* bW2  = (const float*)d_in[8];
    const float* bb2  = (const float*)d_in[9];
    const float* oW1  = (const float*)d_in[10];
    const float* ob1  = (const float*)d_in[11];
    const float* oW2  = (const float*)d_in[12];
    const float* ob2  = (const float*)d_in[13];
    const float* oW3  = (const float*)d_in[14];
    const float* ob3  = (const float*)d_in[15];
    const float* sW   = (const float*)d_in[16];
    const float* sb   = (const float*)d_in[17];

    char* ws = (char*)d_ws;
    constexpr size_t OFF_T    = 0;                     // 5*53*512 f16   =   271,360
    constexpr size_t OFF_HW2T = 271360;                // 128x512 f16    =   131,072
    constexpr size_t OFF_BW2T = 402432;                // 128x512 f16    =   131,072
    constexpr size_t OFF_OW2T = 533504;                // 256x512 f16    =   262,144
    constexpr size_t OFF_OW3T = 795648;                // 128x256 f16    =    65,536
    constexpr size_t OFF_WCT  = 861184;                // 512x2048 f16   = 2,097,152
    constexpr size_t OFF_CID  = 2958336;               // 2048x9 i32     =    73,728
    constexpr size_t OFF_X    = 3032064;               // 2048x2048 f16  = 8,388,608
    constexpr size_t OFF_R1P  = 11420672;              // 4x2048x512 f32 = 16,777,216

    f16*   T    = (f16*)(ws + OFF_T);
    f16*   hW2t = (f16*)(ws + OFF_HW2T);
    f16*   bW2t = (f16*)(ws + OFF_BW2T);
    f16*   oW2t = (f16*)(ws + OFF_OW2T);
    f16*   oW3t = (f16*)(ws + OFF_OW3T);
    f16*   Wct  = (f16*)(ws + OFF_WCT);
    int*   cid  = (int*)(ws + OFF_CID);
    f16*   X    = (f16*)(ws + OFF_X);
    float* R1p  = (float*)(ws + OFF_R1P);

    prep1<<<P1_END, 512, 0, stream>>>(x, emb, hW1, hb1, hW2, bW1, bb1, bW2,
                                      oW2, oW3, T, hW2t, bW2t, oW2t, oW3t, cid);
    mega<<<MG_END, 512, 0, stream>>>(cid, T, hW2t, bW2t, hb2, bb2, oW1, X, Wct);
    combine<<<512, 512, 0, stream>>>(X, Wct, R1p);
    tail2<<<256, 512, 0, stream>>>(R1p, ob1, oW2t, ob2, oW3t, ob3, sW, sb, (float*)d_out);
}

// Round 14
// 53.648 us; speedup vs baseline: 1.0534x; 1.0285x over previous
//
#include <hip/hip_runtime.h>

typedef _Float16 f16;
typedef __attribute__((ext_vector_type(8))) _Float16 f16x8;
typedef __attribute__((ext_vector_type(4))) _Float16 f16x4;
typedef __attribute__((ext_vector_type(4))) float f32x4;
typedef __attribute__((ext_vector_type(16))) float f32x16;

__device__ inline float lrelu(float v){ return v > 0.f ? v : 0.01f*v; }
__device__ inline f16x8 lrelu8(f16x8 v){
    f16x8 z = {};
    f16x8 mx = __builtin_elementwise_max(v, z);
    f16x8 mn = __builtin_elementwise_min(v, z);
    return mx + mn * (f16)0.01f;
}

__device__ __forceinline__ void gload16(const void* gp, void* lp) {
    __builtin_amdgcn_global_load_lds(
        (const __attribute__((address_space(1))) unsigned int*)gp,
        (__attribute__((address_space(3))) unsigned int*)lp,
        16, 0, 0);
}

#define M_ROWS 2048

// ======================= launch 1: all pure-weight prep (no Wct) =======================
//   [0,265)    prep_T ; [265,393) hW2t ; [393,521) bW2t ;
//   [521,777)  oW2t   ; [777,841) oW3t ; [841,845) cards
#define P1_T    0
#define P1_HW2  265
#define P1_BW2  393
#define P1_OW2  521
#define P1_OW3  777
#define P1_CARD 841
#define P1_END  845

__device__ void d_transpose512(const float* __restrict__ in, f16* __restrict__ out,
                               int K, int Nin, int Nout, int b, int tid) {
    int idx = b * 512 + tid;
    if (idx >= Nout * K) return;
    int n = idx / K, k = idx - n * K;
    float v = (n < Nin) ? in[(size_t)k * Nin + n] : 0.f;
    out[idx] = (f16)v;
}

__global__ __launch_bounds__(512) void prep1(const int* __restrict__ x,
                                             const float* __restrict__ emb,
                                             const float* __restrict__ hW1,
                                             const float* __restrict__ hb1,
                                             const float* __restrict__ hW2,
                                             const float* __restrict__ bW1,
                                             const float* __restrict__ bb1,
                                             const float* __restrict__ bW2,
                                             const float* __restrict__ oW2,
                                             const float* __restrict__ oW3,
                                             f16* __restrict__ T,
                                             f16* __restrict__ hW2t,
                                             f16* __restrict__ bW2t,
                                             f16* __restrict__ oW2t,
                                             f16* __restrict__ oW3t,
                                             int* __restrict__ cid) {
    const int bid = blockIdx.x, tid = threadIdx.x;
    if (bid < P1_HW2) {
        int b = bid;                 // slot*53 + card
        int slot = b / 53, card = b - slot * 53;
        const float* W = (slot < 2) ? (hW1 + slot * 64 * 512) : (bW1 + (slot - 2) * 64 * 512);
        const float* e = emb + card * 64;
        float acc = (slot == 1) ? hb1[tid] : ((slot == 4) ? bb1[tid] : 0.f);
        #pragma unroll 8
        for (int k = 0; k < 64; ++k) acc += e[k] * W[k * 512 + tid];
        T[(size_t)b * 512 + tid] = (f16)acc;
    } else if (bid < P1_BW2) {
        d_transpose512(hW2, hW2t, 512, 128, 128, bid - P1_HW2, tid);
    } else if (bid < P1_OW2) {
        d_transpose512(bW2, bW2t, 512, 128, 128, bid - P1_BW2, tid);
    } else if (bid < P1_OW3) {
        d_transpose512(oW2, oW2t, 512, 256, 256, bid - P1_OW2, tid);
    } else if (bid < P1_CARD) {
        d_transpose512(oW3, oW3t, 256, 127, 128, bid - P1_OW3, tid);
    } else {
        int m = (bid - P1_CARD) * 512 + tid;
        if (m >= M_ROWS) return;
        int kh[4], kb[5];
        #pragma unroll
        for (int i = 0; i < 4; ++i) { int r = x[m*18 + 2*i], s = x[m*18 + 2*i + 1]; kh[i] = r*8 + s; }
        #pragma unroll
        for (int i = 0; i < 5; ++i) { int r = x[m*18 + 8 + 2*i], s = x[m*18 + 9 + 2*i]; kb[i] = r*8 + s; }
        #pragma unroll
        for (int i = 1; i < 4; ++i) { int v = kh[i], j = i-1; while (j >= 0 && kh[j] > v) { kh[j+1]=kh[j]; --j; } kh[j+1]=v; }
        #pragma unroll
        for (int i = 1; i < 5; ++i) { int v = kb[i], j = i-1; while (j >= 0 && kb[j] > v) { kb[j+1]=kb[j]; --j; } kb[j+1]=v; }
        #pragma unroll
        for (int i = 0; i < 4; ++i) { int r = kh[i] >> 3, s = kh[i] & 7; cid[m*9 + i] = (r - 1) * s; }
        #pragma unroll
        for (int i = 0; i < 5; ++i) { int r = kb[i] >> 3, s = kb[i] & 7; cid[m*9 + 4 + i] = (r - 1) * s; }
    }
}

// ===== launch 2 (mega): Wct (first: starts HBM stream, overlaps l2) + l2_fused =====
#define MG_L2   256
#define MG_END  768

__global__ __launch_bounds__(512, 4) void mega(const int* __restrict__ cid,
                                               const f16* __restrict__ T,
                                               const f16* __restrict__ hW2t,
                                               const f16* __restrict__ bW2t,
                                               const float* __restrict__ hb2,
                                               const float* __restrict__ bb2,
                                               const float* __restrict__ oW1,
                                               f16* __restrict__ X,
                                               f16* __restrict__ Wct) {
    __shared__ __align__(16) char smem[51200];
    const int bid = blockIdx.x, tid = threadIdx.x;

    if (bid < MG_L2) {
        // ---------------- prep_Wct ----------------
        float (*tile)[65] = (float(*)[65])smem;
        int kb = bid & 31, nb = bid >> 5;
        int nl = tid & 63;
        for (int kl = tid >> 6; kl < 64; kl += 8) {
            int col = kb * 64 + kl;
            int p = col >> 7, r = col & 127;
            int n = nb * 64 + nl;
            float s = 0.f;
            if (p < 6) {
                #pragma unroll
                for (int j = 0; j < 10; ++j) s += oW1[(size_t)((p * 10 + j) * 256 + r) * 512 + n];
            } else {
                int t = p - 6;
                #pragma unroll
                for (int i = 0; i < 6; ++i) s += oW1[(size_t)((i * 10 + t) * 256 + 128 + r) * 512 + n];
            }
            tile[kl][nl] = s;
        }
        __syncthreads();
        for (int nl2 = tid >> 6; nl2 < 64; nl2 += 8) {
            int kl2 = tid & 63;
            Wct[(size_t)(nb * 64 + nl2) * 2048 + kb * 64 + kl2] = (f16)tile[kl2][nl2];
        }
        return;
    }

    // ------- l2_fused: tile 64 rows x 128 cols, K=512, 8 waves of 32r x 32c -------
    f16 (*As)[64*64]  = (f16(*)[64*64])smem;               // 2 x 8KB  (swizzled)
    f16 (*Bs)[128*64] = (f16(*)[128*64])(smem + 16384);    // 2 x 16KB (swizzled)
    const int lbid = bid - MG_L2;
    const bool hero = lbid < 192;
    const int row0 = hero ? lbid * 64 : (lbid - 192) * 64;
    const f16* Bt = hero ? hW2t : bW2t;
    const float* bias = hero ? hb2 : bb2;
    const int lane = tid & 63, wave = tid >> 6;
    const int rw = wave & 1, cw = wave >> 1;   // 2 rowg x 4 colg
    const int l31 = lane & 31, lh = lane >> 5;

    const int br = tid >> 3, bchunk = tid & 7;   // A-build: row br, chunk bchunk
    const int grow = row0 + br;
    const f16 *t0, *t1, *t2;
    if (hero) {
        const int HP0[6] = {0,0,0,1,1,2}, HP1[6] = {1,2,3,2,3,3};
        int m = grow / 6, p = grow - m * 6;
        t0 = T + (size_t)(0*53 + cid[m*9 + HP0[p]]) * 512;
        t1 = T + (size_t)(1*53 + cid[m*9 + HP1[p]]) * 512;
        t2 = T;   // slot0 card0 == all zeros
    } else {
        const int BT0[10] = {4,4,4,4,4,4,5,5,5,6};
        const int BT1[10] = {5,5,5,6,6,7,6,6,7,7};
        const int BT2[10] = {6,7,8,7,8,8,7,8,8,8};
        int m = grow / 10, t = grow - m * 10;
        t0 = T + (size_t)(2*53 + cid[m*9 + BT0[t]]) * 512;
        t1 = T + (size_t)(3*53 + cid[m*9 + BT1[t]]) * 512;
        t2 = T + (size_t)(4*53 + cid[m*9 + BT2[t]]) * 512;
    }

    auto stageB = [&](int buf, int k0) {
        #pragma unroll
        for (int i = 0; i < 2; ++i) {
            int c = tid + i * 512;                 // 1024 chunks: 128 rows x 8
            int r = c >> 3, cc = c & 7;
            gload16(Bt + (size_t)r * 512 + k0 + ((cc ^ (r & 7)) << 3), (void*)&Bs[buf][c * 8]);
        }
    };
    auto buildA = [&](int buf, int k0) {
        f16x8 a = *(const f16x8*)(t0 + k0 + bchunk * 8);
        f16x8 b = *(const f16x8*)(t1 + k0 + bchunk * 8);
        f16x8 c = *(const f16x8*)(t2 + k0 + bchunk * 8);
        *(f16x8*)&As[buf][br * 64 + ((bchunk ^ (br & 7)) << 3)] = lrelu8(a + b + c);
    };

    f32x16 acc = {};
    stageB(0, 0); buildA(0, 0);
    __syncthreads();
    for (int t = 0; t < 8; ++t) {
        int cur = t & 1;
        if (t < 7) { stageB(cur ^ 1, (t + 1) * 64); buildA(cur ^ 1, (t + 1) * 64); }
        #pragma unroll
        for (int ks4 = 0; ks4 < 4; ++ks4) {
            int chunk = ks4 * 2 + lh;
            int ar = rw * 32 + l31, bcol = cw * 32 + l31;
            f16x8 a = *(const f16x8*)&As[cur][ar * 64 + ((chunk ^ (ar & 7)) << 3)];
            f16x8 b = *(const f16x8*)&Bs[cur][bcol * 64 + ((chunk ^ (bcol & 7)) << 3)];
            acc = __builtin_amdgcn_mfma_f32_32x32x16_f16(a, b, acc, 0, 0, 0);
        }
        __syncthreads();
    }
    #pragma unroll
    for (int q = 0; q < 16; ++q) {
        int row = row0 + rw * 32 + (q & 3) + 8 * (q >> 2) + 4 * lh;
        int col = cw * 32 + l31;
        float v = lrelu(acc[q] + bias[col]);
        size_t off;
        if (hero) { int m = row / 6,  p = row - m*6;  off = (size_t)m*2048 + p*128 + col; }
        else      { int m = row / 10, p = row - m*10; off = (size_t)m*2048 + 768 + p*128 + col; }
        X[off] = (f16)v;
    }
}

// ===== launch 3: combine, split-K=4, BN=128, XCD-swizzled, 32x32x16 MFMA =====
__global__ __launch_bounds__(512, 4) void combine(const f16* __restrict__ X,
                                                  const f16* __restrict__ Wct,
                                                  float* __restrict__ R1p) {
    __shared__ __align__(16) f16 As[2][64 * 64];    // 16KB
    __shared__ __align__(16) f16 Bs[2][128 * 64];   // 32KB
    const int bid = blockIdx.x;                     // 0..511
    const int xcd = bid & 7, slot = bid >> 3;       // slot 0..63
    const int rp = xcd * 4 + (slot & 3);            // row panel 0..31 (same rp -> same XCD)
    const int rest = slot >> 2;                     // 0..15
    const int cp = rest & 3, ks = rest >> 2;        // col panel 0..3, k-split 0..3
    const int row0 = rp * 64, col0 = cp * 128, k0b = ks * 512;
    const int tid = threadIdx.x, lane = tid & 63, wave = tid >> 6;
    const int rw = wave & 1, cw = wave >> 1;        // 2 rowg x 4 colg of 32
    const int l31 = lane & 31, lh = lane >> 5;

    auto stage = [&](int buf, int k0) {
        { int r = tid >> 3, cc = tid & 7;
          gload16(X + (size_t)(row0 + r) * 2048 + k0 + ((cc ^ (r & 7)) << 3), (void*)&As[buf][tid * 8]); }
        #pragma unroll
        for (int i = 0; i < 2; ++i) {
            int c = tid + i * 512;
            int r = c >> 3, cc = c & 7;
            gload16(Wct + (size_t)(col0 + r) * 2048 + k0 + ((cc ^ (r & 7)) << 3), (void*)&Bs[buf][c * 8]);
        }
    };

    f32x16 acc = {};
    stage(0, k0b);
    __syncthreads();
    for (int t = 0; t < 8; ++t) {
        int cur = t & 1;
        if (t < 7) stage(cur ^ 1, k0b + (t + 1) * 64);
        #pragma unroll
        for (int ks4 = 0; ks4 < 4; ++ks4) {
            int chunk = ks4 * 2 + lh;
            int ar = rw * 32 + l31, bcol = cw * 32 + l31;
            f16x8 a = *(const f16x8*)&As[cur][ar * 64 + ((chunk ^ (ar & 7)) << 3)];
            f16x8 b = *(const f16x8*)&Bs[cur][bcol * 64 + ((chunk ^ (bcol & 7)) << 3)];
            acc = __builtin_amdgcn_mfma_f32_32x32x16_f16(a, b, acc, 0, 0, 0);
        }
        __syncthreads();
    }
    float* dst = R1p + (size_t)ks * 2048 * 512;
    #pragma unroll
    for (int q = 0; q < 16; ++q) {
        int row = row0 + rw * 32 + (q & 3) + 8 * (q >> 2) + 4 * lh;
        int col = col0 + cw * 32 + l31;
        dst[(size_t)row * 512 + col] = acc[q];
    }
}

// ===== launch 4: tail2, 256 blocks x 8 rows: sum 4 slices + ob1 -> R2 -> R3 -> out ====
__global__ __launch_bounds__(512, 2) void tail2(const float* __restrict__ R1p,
                                                const float* __restrict__ ob1,
                                                const f16* __restrict__ oW2t,
                                                const float* __restrict__ ob2,
                                                const f16* __restrict__ oW3t,
                                                const float* __restrict__ ob3,
                                                const float* __restrict__ sW,
                                                const float* __restrict__ sb,
                                                float* __restrict__ out) {
    __shared__ __align__(16) f16 A1s[16 * 512];     // 16KB (rows 8-15 zeroed)
    __shared__ __align__(16) f16 Bs[2][256 * 64];   // 64KB
    __shared__ __align__(16) f16 R2s[16 * 256];     // 8KB
    __shared__ float R3s[16][132];
    __shared__ float sWs[127 * 9];
    __shared__ float sbs[9];
    const int row0 = blockIdx.x * 8;
    const int tid = threadIdx.x, lane = tid & 63, wave = tid >> 6;
    const int lr = lane & 15;

    auto stageB2 = [&](int buf, int t) {            // oW2t: 256 rows x 8 chunks = 2048
        #pragma unroll
        for (int i = 0; i < 4; ++i) {
            int c = tid + i * 512;
            int r = c >> 3, cc = c & 7;
            gload16(oW2t + (size_t)r * 512 + t * 64 + ((cc ^ (r & 7)) << 3), (void*)&Bs[buf][c * 8]);
        }
    };
    stageB2(0, 0);                                  // overlap with phase A

    // --- phase A: A1[0:8] = lrelu(sum 4 R1p slices + ob1) -> swizzled f16; A1[8:16]=0 ---
    #pragma unroll
    for (int i = 0; i < 2; ++i) {
        int g = tid + i * 512;                      // 1024 f32x4 groups (8 rows x 128)
        int row = g >> 7, c4 = (g & 127) << 2;
        f32x4 v = *(const f32x4*)(ob1 + c4);
        #pragma unroll
        for (int s = 0; s < 4; ++s)
            v += *(const f32x4*)(R1p + (size_t)s * 2048 * 512 + (size_t)(row0 + row) * 512 + c4);
        f16x4 p;
        #pragma unroll
        for (int q = 0; q < 4; ++q) p[q] = (f16)lrelu(v[q]);
        int chunk = c4 >> 3, half = (c4 >> 2) & 1;
        *(f16x4*)&A1s[row * 512 + ((chunk ^ (row & 7)) << 3) + half * 4] = p;
    }
    {   // zero rows 8..15 (512 f16x8 chunks)
        f16x8 z = {};
        int row = 8 + (tid >> 6), chunk = tid & 63;
        *(f16x8*)&A1s[row * 512 + chunk * 8] = z;
    }
    for (int i = tid; i < 127 * 9; i += 512) sWs[i] = sW[i];
    if (tid < 9) sbs[tid] = sb[tid];
    __syncthreads();

    // --- phase B: R2 = lrelu(A1 @ oW2t^T + ob2), 16(8 valid)x256, K=512, 8 steps ---
    f32x4 acc2[2] = {};
    for (int t = 0; t < 8; ++t) {
        int cur = t & 1;
        if (t < 7) stageB2(cur ^ 1, t + 1);
        #pragma unroll
        for (int kk2 = 0; kk2 < 2; ++kk2) {
            int g  = kk2 * 4 + (lane >> 4);
            int gg = t * 8 + g;
            f16x8 a = *(const f16x8*)&A1s[lr * 512 + ((gg ^ (lr & 7)) << 3)];
            int eo = (g ^ (lr & 7)) << 3;
            #pragma unroll
            for (int j = 0; j < 2; ++j) {
                f16x8 b = *(const f16x8*)&Bs[cur][(wave * 32 + j * 16 + lr) * 64 + eo];
                acc2[j] = __builtin_amdgcn_mfma_f32_16x16x32_f16(a, b, acc2[j], 0, 0, 0);
            }
        }
        __syncthreads();
    }
    #pragma unroll
    for (int j = 0; j < 2; ++j)
    #pragma unroll
    for (int q = 0; q < 4; ++q) {
        int row = (lane >> 4) * 4 + q;              // rows 8-15 hold lrelu(ob2): finite, unused
        int col = wave * 32 + j * 16 + lr;
        f16 v = (f16)lrelu(acc2[j][q] + ob2[col]);
        int chunk = col >> 3, w = col & 7;
        R2s[row * 256 + ((chunk ^ (row & 7)) << 3) + w] = v;
    }
    auto stageB3 = [&](int buf, int t) {            // oW3t: 128 rows x 8 chunks = 1024
        #pragma unroll
        for (int i = 0; i < 2; ++i) {
            int c = tid + i * 512;
            if (c < 1024) {
                int r = c >> 3, cc = c & 7;
                gload16(oW3t + (size_t)r * 256 + t * 64 + ((cc ^ (r & 7)) << 3), (void*)&Bs[buf][c * 8]);
            }
        }
    };
    stageB3(0, 0);
    __syncthreads();

    // --- phase C: R3 = lrelu(R2 @ oW3t^T + ob3), 16(8 valid)x128, K=256, 4 steps ---
    f32x4 acc3 = {};
    for (int t = 0; t < 4; ++t) {
        int cur = t & 1;
        if (t < 3) stageB3(cur ^ 1, t + 1);
        #pragma unroll
        for (int kk2 = 0; kk2 < 2; ++kk2) {
            int g  = kk2 * 4 + (lane >> 4);
            int gg = t * 8 + g;
            f16x8 a = *(const f16x8*)&R2s[lr * 256 + ((gg ^ (lr & 7)) << 3)];
            int eo = (g ^ (lr & 7)) << 3;
            f16x8 b = *(const f16x8*)&Bs[cur][(wave * 16 + lr) * 64 + eo];
            acc3 = __builtin_amdgcn_mfma_f32_16x16x32_f16(a, b, acc3, 0, 0, 0);
        }
        __syncthreads();
    }
    #pragma unroll
    for (int q = 0; q < 4; ++q) {
        int row = (lane >> 4) * 4 + q;
        int col = wave * 16 + lr;
        R3s[row][col] = lrelu(acc3[q] + ((col < 127) ? ob3[col] : 0.f));
    }
    __syncthreads();

    // --- phase D: out = R3 @ sW + sb (rows 0..7 only) ---
    if (tid < 8 * 9) {
        int row = tid / 9, a = tid - row * 9;
        float s = sbs[a];
        #pragma unroll 4
        for (int n = 0; n < 127; ++n) s += R3s[row][n] * sWs[n * 9 + a];
        out[(size_t)(row0 + row) * 9 + a] = s;
    }
}

extern "C" void kernel_launch(void* const* d_in, const int* in_sizes, int n_in,
                              void* d_out, int out_size, void* d_ws, size_t ws_size,
                              hipStream_t stream) {
    const int*   x    = (const int*)  d_in[0];
    const float* emb  = (const float*)d_in[1];
    const float* hW1  = (const float*)d_in[2];
    const float* hb1  = (const float*)d_in[3];
    const float* hW2  = (const float*)d_in[4];
    const float* hb2  = (const float*)d_in[5];
    const float* bW1  = (const float*)d_in[6];
    const float* bb1  = (const float*)d_in[7];
    const float* bW2  = (const float*)d_in[8];
    const float* bb2  = (const float*)d_in[9];
    const float* oW1  = (const float*)d_in[10];
    const float* ob1  = (const float*)d_in[11];
    const float* oW2  = (const float*)d_in[12];
    const float* ob2  = (const float*)d_in[13];
    const float* oW3  = (const float*)d_in[14];
    const float* ob3  = (const float*)d_in[15];
    const float* sW   = (const float*)d_in[16];
    const float* sb   = (const float*)d_in[17];

    char* ws = (char*)d_ws;
    constexpr size_t OFF_T    = 0;                     // 5*53*512 f16   =   271,360
    constexpr size_t OFF_HW2T = 271360;                // 128x512 f16    =   131,072
    constexpr size_t OFF_BW2T = 402432;                // 128x512 f16    =   131,072
    constexpr size_t OFF_OW2T = 533504;                // 256x512 f16    =   262,144
    constexpr size_t OFF_OW3T = 795648;                // 128x256 f16    =    65,536
    constexpr size_t OFF_WCT  = 861184;                // 512x2048 f16   = 2,097,152
    constexpr size_t OFF_CID  = 2958336;               // 2048x9 i32     =    73,728
    constexpr size_t OFF_X    = 3032064;               // 2048x2048 f16  = 8,388,608
    constexpr size_t OFF_R1P  = 11420672;              // 4x2048x512 f32 = 16,777,216

    f16*   T    = (f16*)(ws + OFF_T);
    f16*   hW2t = (f16*)(ws + OFF_HW2T);
    f16*   bW2t = (f16*)(ws + OFF_BW2T);
    f16*   oW2t = (f16*)(ws + OFF_OW2T);
    f16*   oW3t = (f16*)(ws + OFF_OW3T);
    f16*   Wct  = (f16*)(ws + OFF_WCT);
    int*   cid  = (int*)(ws + OFF_CID);
    f16*   X    = (f16*)(ws + OFF_X);
    float* R1p  = (float*)(ws + OFF_R1P);

    prep1<<<P1_END, 512, 0, stream>>>(x, emb, hW1, hb1, hW2, bW1, bb1, bW2,
                                      oW2, oW3, T, hW2t, bW2t, oW2t, oW3t, cid);
    mega<<<MG_END, 512, 0, stream>>>(cid, T, hW2t, bW2t, hb2, bb2, oW1, X, Wct);
    combine<<<512, 512, 0, stream>>>(X, Wct, R1p);
    tail2<<<256, 512, 0, stream>>>(R1p, ob1, oW2t, ob2, oW3t, ob3, sW, sb, (float*)d_out);
}